// Round 5
// baseline (3023.762 us; speedup 1.0000x reference)
//
#include <hip/hip_runtime.h>

// LSTM B=1024 T=512 H=256 (input_size=1, output_size=1) on MI355X.
// R5: 64 blocks (1/CU) x 1024 thr = 16 waves = 4 waves/SIMD (TLP attack #2).
// Wave w owns the full gate set of hidden segment w (16 units): tiles
//   i: Tn=w (register-resident, 32 regs, MFMA-B-only)
//   f: Tn=16+w (LDS-resident; 16 tiles = 128 KB staged once)
//   g: Tn=32+w, o: Tn=48+w (streamed from L2, 2-fragment lookahead, 16 regs)
// K-loop is kc-MAJOR: per kc one A-frag feeds 4 MFMAs (i,f,g,o) -> A/B frags
// are 2-slot pipelined transients; worst-case live ~120 regs (128-reg cap via
// __launch_bounds__(1024,4)).
// Custom LDS-only barrier (s_waitcnt lgkmcnt(0); s_barrier): __syncthreads'
// vmcnt(0) drain killed R3/R4 cross-step prefetch; W-stream + x prefetch now
// genuinely ride the barrier. Lane-local c/h update; h via LDS bf16 dbuf
// (stride 264); ONE barrier per step.

#define HID 256
#define TT 512
#define BROWS 16
#define NBLK 64
#define THREADS 1024
#define HPAD 264

typedef float v4f __attribute__((ext_vector_type(4)));
typedef unsigned int v4u __attribute__((ext_vector_type(4)));
typedef __bf16 v8bf __attribute__((ext_vector_type(8)));

__device__ __forceinline__ unsigned short f2bf(float f) {
    unsigned int u = __builtin_bit_cast(unsigned int, f);
    u += 0x7fffu + ((u >> 16) & 1u);   // RNE
    return (unsigned short)(u >> 16);
}
__device__ __forceinline__ float bf2f(unsigned short s) {
    unsigned int u = ((unsigned int)s) << 16;
    return __builtin_bit_cast(float, u);
}
__device__ __forceinline__ float fsigmoid(float x) {
    float e = exp2f(x * -1.44269504f);
    return __builtin_amdgcn_rcpf(1.0f + e);
}
__device__ __forceinline__ float ftanh(float x) {
    float e = exp2f(x * 2.88539008f);
    return 1.0f - 2.0f * __builtin_amdgcn_rcpf(1.0f + e);
}

// W_hh fp32 [1024][256] -> bf16 fragment order:
// Wbf[((Tn*8+kc)*64+lane)*8 + j] = bf16(W_hh[16*Tn+(lane&15)][32*kc+(lane>>4)*8+j])
__global__ void wconv_kernel(const float* __restrict__ Whh,
                             unsigned short* __restrict__ Wbf) {
    int tid = blockIdx.x * blockDim.x + threadIdx.x;   // 0..32767
    int lane = tid & 63;
    int frag = tid >> 6;
    int Tn = frag >> 3;
    int kc = frag & 7;
    int n  = Tn * 16 + (lane & 15);
    int kb = kc * 32 + (lane >> 4) * 8;
    const float* src = Whh + (size_t)n * HID + kb;
    unsigned short* dst = Wbf + (size_t)tid * 8;
#pragma unroll
    for (int j = 0; j < 8; ++j) dst[j] = f2bf(src[j]);
}

__global__ __launch_bounds__(THREADS, 4)
void lstm_kernel(const float* __restrict__ x,
                 const float* __restrict__ W_ih,
                 const float* __restrict__ b_ih,
                 const float* __restrict__ b_hh,
                 const float* __restrict__ W_lin,
                 const float* __restrict__ b_lin,
                 const unsigned short* __restrict__ Wbf,
                 float* __restrict__ out) {
    __shared__ __align__(16) unsigned short Wlds[16 * 8 * 64 * 8];   // 128 KB (f-tiles)
    __shared__ __align__(16) unsigned short hbuf[2][BROWS * HPAD];   // 16.5 KB

    const int tid  = threadIdx.x;
    const int lane = tid & 63;
    const int w    = tid >> 6;      // wave 0..15 = hidden segment
    const int l4   = lane & 15;
    const int quad = lane >> 4;
    const int r0   = blockIdx.x * BROWS;

    // Per-lane gate constants in registers (hidden unit n_ = 16*w + l4).
    const int n_ = 16 * w + l4;
    const float wi0 = W_ih[n_],       bb0 = b_ih[n_]       + b_hh[n_];
    const float wi1 = W_ih[256 + n_], bb1 = b_ih[256 + n_] + b_hh[256 + n_];
    const float wi2 = W_ih[512 + n_], bb2 = b_ih[512 + n_] + b_hh[512 + n_];
    const float wi3 = W_ih[768 + n_], bb3 = b_ih[768 + n_] + b_hh[768 + n_];

    const v4u* __restrict__ Wv = (const v4u*)Wbf;   // 16B frags: idx (Tn*8+kc)*64+lane

    // i-tile -> registers (MFMA-B only -> AGPR-eligible)
    v8bf wires[8];
#pragma unroll
    for (int kc = 0; kc < 8; ++kc)
        wires[kc] = __builtin_bit_cast(v8bf, Wv[((size_t)w * 8 + kc) * 64 + lane]);
    // f-tile -> LDS slot w
#pragma unroll
    for (int kc = 0; kc < 8; ++kc) {
        v4u d = Wv[((size_t)(16 + w) * 8 + kc) * 64 + lane];
        *(v4u*)(Wlds + ((size_t)((w * 8 + kc) * 64 + lane)) * 8) = d;
    }
    // h(0) = 0
    for (int i = tid; i < BROWS * HPAD; i += THREADS) hbuf[0][i] = 0;
    __syncthreads();

    // stream bases for g,o tiles
    const v4u* __restrict__ gbase = Wv + ((size_t)(32 + w) * 8) * 64 + lane;
    const v4u* __restrict__ obase = Wv + ((size_t)(48 + w) * 8) * 64 + lane;

    v8bf sbg[2], sbo[2];
    sbg[0] = __builtin_bit_cast(v8bf, gbase[0]);
    sbg[1] = __builtin_bit_cast(v8bf, gbase[64]);
    sbo[0] = __builtin_bit_cast(v8bf, obase[0]);
    sbo[1] = __builtin_bit_cast(v8bf, obase[64]);

    float c0 = 0.f, c1 = 0.f, c2 = 0.f, c3 = 0.f;

    // x for t=0 (rows m = quad*4 + r; same addr across l4 lanes -> broadcast)
    float xv0 = x[(size_t)(r0 + quad * 4 + 0) * TT];
    float xv1 = x[(size_t)(r0 + quad * 4 + 1) * TT];
    float xv2 = x[(size_t)(r0 + quad * 4 + 2) * TT];
    float xv3 = x[(size_t)(r0 + quad * 4 + 3) * TT];

    int cur = 0;
    for (int t = 0; t < TT; ++t) {
        const unsigned short* hrow = &hbuf[cur][l4 * HPAD + quad * 8];
        unsigned short* hn_ = hbuf[cur ^ 1];

        // acc init = x*W_ih + bias
        v4f ai, af2, ag, ao;
        ai[0] = xv0 * wi0 + bb0; ai[1] = xv1 * wi0 + bb0;
        ai[2] = xv2 * wi0 + bb0; ai[3] = xv3 * wi0 + bb0;
        af2[0] = xv0 * wi1 + bb1; af2[1] = xv1 * wi1 + bb1;
        af2[2] = xv2 * wi1 + bb1; af2[3] = xv3 * wi1 + bb1;
        ag[0] = xv0 * wi2 + bb2; ag[1] = xv1 * wi2 + bb2;
        ag[2] = xv2 * wi2 + bb2; ag[3] = xv3 * wi2 + bb2;
        ao[0] = xv0 * wi3 + bb3; ao[1] = xv1 * wi3 + bb3;
        ao[2] = xv2 * wi3 + bb3; ao[3] = xv3 * wi3 + bb3;

        // A-fragment pipeline (2-slot)
        v8bf af_[2];
        af_[0] = __builtin_bit_cast(v8bf, *(const v4u*)(hrow));

#pragma unroll
        for (int kc = 0; kc < 8; ++kc) {
            if (kc < 7)
                af_[(kc + 1) & 1] = __builtin_bit_cast(v8bf,
                    *(const v4u*)(hrow + (kc + 1) * 32));
            v8bf fB = __builtin_bit_cast(v8bf,
                *(const v4u*)(Wlds + ((size_t)((w * 8 + kc) * 64 + lane)) * 8));
            v8bf a = af_[kc & 1];
            ai  = __builtin_amdgcn_mfma_f32_16x16x32_bf16(a, wires[kc], ai, 0, 0, 0);
            af2 = __builtin_amdgcn_mfma_f32_16x16x32_bf16(a, fB,        af2, 0, 0, 0);
            ag  = __builtin_amdgcn_mfma_f32_16x16x32_bf16(a, sbg[kc & 1], ag, 0, 0, 0);
            ao  = __builtin_amdgcn_mfma_f32_16x16x32_bf16(a, sbo[kc & 1], ao, 0, 0, 0);
            // refill consumed slot with frag kc+2 (data identical every step;
            // kc=6,7 issue t+1's kc=0,1 -> in flight across the barrier)
            sbg[kc & 1] = __builtin_bit_cast(v8bf, gbase[((kc + 2) & 7) * 64]);
            sbo[kc & 1] = __builtin_bit_cast(v8bf, obase[((kc + 2) & 7) * 64]);
        }

        // gates + state update (lane-local: unit n_, rows m=quad*4+r)
#pragma unroll
        for (int r = 0; r < 4; ++r) {
            float gi = fsigmoid(ai[r]);
            float gf = fsigmoid(af2[r]);
            float gg = ftanh(ag[r]);
            float go = fsigmoid(ao[r]);
            float cp = (r == 0) ? c0 : (r == 1) ? c1 : (r == 2) ? c2 : c3;
            float cn = gf * cp + gi * gg;
            if (r == 0) c0 = cn; else if (r == 1) c1 = cn;
            else if (r == 2) c2 = cn; else c3 = cn;
            hn_[(quad * 4 + r) * HPAD + n_] = f2bf(go * ftanh(cn));
        }

        // x prefetch for t+1 (rides the LDS-only barrier)
        if (t + 1 < TT) {
            xv0 = x[(size_t)(r0 + quad * 4 + 0) * TT + t + 1];
            xv1 = x[(size_t)(r0 + quad * 4 + 1) * TT + t + 1];
            xv2 = x[(size_t)(r0 + quad * 4 + 2) * TT + t + 1];
            xv3 = x[(size_t)(r0 + quad * 4 + 3) * TT + t + 1];
        }

        // LDS-only barrier: h-writes (DS) drained via lgkmcnt(0); in-flight
        // global W/x prefetches (vmcnt) intentionally NOT drained.
        asm volatile("s_waitcnt lgkmcnt(0)\n\ts_barrier" ::: "memory");
        cur ^= 1;
    }

    // Epilogue: out[b] = h_final . W_lin + b_lin   (overlay partials on Wlds)
    float* part = (float*)Wlds;
    {
        int rrow = tid >> 6, seg = tid & 63;
        float p = 0.0f;
#pragma unroll
        for (int jj = 0; jj < 4; ++jj) {
            int j = seg * 4 + jj;
            p += bf2f(hbuf[cur][rrow * HPAD + j]) * W_lin[j];
        }
        part[tid] = p;
    }
    __syncthreads();
    if (tid < 16) {
        float sum = 0.0f;
#pragma unroll
        for (int s = 0; s < 64; ++s) sum += part[tid * 64 + s];
        out[r0 + tid] = sum + b_lin[0];
    }
}

extern "C" void kernel_launch(void* const* d_in, const int* in_sizes, int n_in,
                              void* d_out, int out_size, void* d_ws, size_t ws_size,
                              hipStream_t stream) {
    const float* x     = (const float*)d_in[0];
    const float* W_ih  = (const float*)d_in[1];
    const float* W_hh  = (const float*)d_in[2];
    const float* b_ih  = (const float*)d_in[3];
    const float* b_hh  = (const float*)d_in[4];
    const float* W_lin = (const float*)d_in[5];
    const float* b_lin = (const float*)d_in[6];
    unsigned short* Wbf = (unsigned short*)d_ws;   // 512 KB

    wconv_kernel<<<128, 256, 0, stream>>>(W_hh, Wbf);
    lstm_kernel<<<NBLK, THREADS, 0, stream>>>(x, W_ih, b_ih, b_hh, W_lin, b_lin,
                                              Wbf, (float*)d_out);
}

// Round 6
// 1861.390 us; speedup vs baseline: 1.6245x; 1.6245x over previous
//
#include <hip/hip_runtime.h>

// LSTM B=1024 T=512 H=256 (input_size=1, output_size=1) on MI355X.
// R6 = R4 (64 blocks x 512 thr = 8 waves, 2/SIMD; proven spill-free) + stall cuts:
//  (a) hbuf XOR swizzle: HPAD 264->256, granule pos = g ^ row. R4's A-frag read
//      was 8-way bank-conflicted (row stride 132 dw = 4 mod 32); swizzle makes
//      every wave read perfectly bank-balanced. h-writes use matching swizzle.
//  (b) LDS-only barrier (s_waitcnt lgkmcnt(0); s_barrier): __syncthreads drains
//      vmcnt(0), killing cross-step prefetch. h traffic is DS -> lgkmcnt covers it.
//  (c) o-tiles (2/wave) streamed from L2 via 4-frag rotating lookahead; refill
//      of frag kc+4 issued at consumption of kc -> t+1 frags in flight across
//      the barrier (now legal thanks to (b)).
//  (d) x for t+1 prefetched mid-step (after last INITG use), rides the barrier.
// Per wave w: i,f tiles (4) in regs/AGPRs (128), g tiles (2) LDS-resident
// (16 tiles = 128 KB), o tiles (2) streamed. Budget: 2 waves/SIMD = 256 unified
// regs; est ~246. Canary: WRITE_SIZE balloons => spilled => back off.

#define HID 256
#define TT 512
#define BROWS 16
#define NBLK 64
#define THREADS 512

typedef float v4f __attribute__((ext_vector_type(4)));
typedef unsigned int v4u __attribute__((ext_vector_type(4)));
typedef __bf16 v8bf __attribute__((ext_vector_type(8)));

__device__ __forceinline__ unsigned short f2bf(float f) {
    unsigned int u = __builtin_bit_cast(unsigned int, f);
    u += 0x7fffu + ((u >> 16) & 1u);   // RNE
    return (unsigned short)(u >> 16);
}
__device__ __forceinline__ float bf2f(unsigned short s) {
    unsigned int u = ((unsigned int)s) << 16;
    return __builtin_bit_cast(float, u);
}
__device__ __forceinline__ float fsigmoid(float x) {
    float e = exp2f(x * -1.44269504f);
    return __builtin_amdgcn_rcpf(1.0f + e);
}
__device__ __forceinline__ float ftanh(float x) {
    float e = exp2f(x * 2.88539008f);
    return 1.0f - 2.0f * __builtin_amdgcn_rcpf(1.0f + e);
}

// W_hh fp32 [1024][256] -> bf16 fragment order:
// Wbf[((Tn*8+kc)*64+lane)*8 + j] = bf16(W_hh[16*Tn+(lane&15)][32*kc+(lane>>4)*8+j])
__global__ void wconv_kernel(const float* __restrict__ Whh,
                             unsigned short* __restrict__ Wbf) {
    int tid = blockIdx.x * blockDim.x + threadIdx.x;   // 0..32767
    int lane = tid & 63;
    int frag = tid >> 6;
    int Tn = frag >> 3;
    int kc = frag & 7;
    int n  = Tn * 16 + (lane & 15);
    int kb = kc * 32 + (lane >> 4) * 8;
    const float* src = Whh + (size_t)n * HID + kb;
    unsigned short* dst = Wbf + (size_t)tid * 8;
#pragma unroll
    for (int j = 0; j < 8; ++j) dst[j] = f2bf(src[j]);
}

#define MFMA8(ACC, BARR, BOFF)                                               \
    _Pragma("unroll")                                                        \
    for (int kc = 0; kc < 8; ++kc)                                           \
        ACC = __builtin_amdgcn_mfma_f32_16x16x32_bf16(afrag[kc],             \
                  BARR[(BOFF) + kc], ACC, 0, 0, 0);

// LDS-resident g-tile, slot = w*2 + S (sequential lane-contiguous: conflict-free)
#define LDSTILE(ACC, SLOT)                                                   \
    { v8bf bl_[8];                                                           \
      _Pragma("unroll")                                                      \
      for (int kc = 0; kc < 8; ++kc)                                         \
          bl_[kc] = __builtin_bit_cast(v8bf, *(const v4u*)(Wlds +            \
                      ((size_t)(((SLOT) * 8 + kc) * 64 + lane)) * 8));       \
      MFMA8(ACC, bl_, 0) }

// streamed o-tile: consume rotating 4-slot buffer, refill frag kc+4
// ((kc+4)&7 for kc>=4 -> next step's frags, in flight across the barrier)
#define STREAMTILE(ACC, SO, OBASE)                                           \
    _Pragma("unroll")                                                        \
    for (int kc = 0; kc < 8; ++kc) {                                         \
        ACC = __builtin_amdgcn_mfma_f32_16x16x32_bf16(afrag[kc],             \
                  SO[kc & 3], ACC, 0, 0, 0);                                 \
        SO[kc & 3] = __builtin_bit_cast(v8bf, OBASE[((kc + 4) & 7) * 64]);   \
    }

#define INITG(S, AI, AF, AG, AO)                                             \
    { int nb = 16 * (w + 8 * (S)) + l4;                                      \
      float w0 = gw[nb],       b0 = gb[nb];                                  \
      float w1 = gw[256 + nb], b1 = gb[256 + nb];                            \
      float w2 = gw[512 + nb], b2 = gb[512 + nb];                            \
      float w3 = gw[768 + nb], b3 = gb[768 + nb];                            \
      _Pragma("unroll")                                                      \
      for (int r = 0; r < 4; ++r) {                                          \
          AI[r] = xv[r] * w0 + b0; AF[r] = xv[r] * w1 + b1;                  \
          AG[r] = xv[r] * w2 + b2; AO[r] = xv[r] * w3 + b3; } }

// swizzled h-write: unit n_ = 16*(w+8S)+l4, row m = quad*4+r
#define GATES(S, AI, AF, AG, AO)                                             \
    { int n_ = 16 * (w + 8 * (S)) + l4;                                      \
      int gn = n_ >> 3;                                                      \
      _Pragma("unroll")                                                      \
      for (int r = 0; r < 4; ++r) {                                          \
        float gi = fsigmoid(AI[r]);                                          \
        float gf = fsigmoid(AF[r]);                                          \
        float gg = ftanh(AG[r]);                                             \
        float go = fsigmoid(AO[r]);                                          \
        float cn = gf * c_st[(S) * 4 + r] + gi * gg;                         \
        c_st[(S) * 4 + r] = cn;                                              \
        int m = quad * 4 + r;                                                \
        hn_[m * 256 + ((gn ^ m) & 31) * 8 + (n_ & 7)] = f2bf(go * ftanh(cn));\
      } }

__global__ __launch_bounds__(THREADS, 2)
void lstm_kernel(const float* __restrict__ x,
                 const float* __restrict__ W_ih,
                 const float* __restrict__ b_ih,
                 const float* __restrict__ b_hh,
                 const float* __restrict__ W_lin,
                 const float* __restrict__ b_lin,
                 const unsigned short* __restrict__ Wbf,
                 float* __restrict__ out) {
    __shared__ __align__(16) unsigned short Wlds[16 * 8 * 64 * 8];   // 128 KB (g-tiles)
    __shared__ __align__(16) unsigned short hbuf[2][BROWS * 256];    // 16 KB, XOR-swizzled
    __shared__ float gw[1024];                                       // 4 KB
    __shared__ float gb[1024];                                       // 4 KB
    __shared__ float part[THREADS];                                  // 2 KB

    const int tid  = threadIdx.x;
    const int lane = tid & 63;
    const int w    = tid >> 6;      // wave 0..7
    const int l4   = lane & 15;
    const int quad = lane >> 4;
    const int r0   = blockIdx.x * BROWS;

    // gate consts -> LDS
    for (int i = tid; i < 1024; i += THREADS) {
        gw[i] = W_ih[i];
        gb[i] = b_ih[i] + b_hh[i];
    }
    // h(0) = 0 (both buffers; swizzle irrelevant for zeros)
    for (int i = tid; i < BROWS * 256; i += THREADS) {
        hbuf[0][i] = 0;
        hbuf[1][i] = 0;
    }

    const v4u* __restrict__ Wv = (const v4u*)Wbf;   // frag idx (Tn*8+kc)*64+lane

    // register/AGPR-resident i,f tiles: [0]=i,S0(Tn=w) [1]=f,S0(16+w) [2]=i,S1(8+w) [3]=f,S1(24+w)
    v8bf wres[32];
    {
        const int tns[4] = {w, 16 + w, 8 + w, 24 + w};
#pragma unroll
        for (int qq = 0; qq < 4; ++qq)
#pragma unroll
            for (int kc = 0; kc < 8; ++kc)
                wres[qq * 8 + kc] = __builtin_bit_cast(v8bf,
                    Wv[((size_t)(tns[qq]) * 8 + kc) * 64 + lane]);
    }
    // LDS-resident g-tiles: slot w*2+S <- Tn = 32 + w + 8*S
#pragma unroll
    for (int S = 0; S < 2; ++S) {
        int Tn = 32 + w + 8 * S;
        int slot = w * 2 + S;
#pragma unroll
        for (int kc = 0; kc < 8; ++kc) {
            v4u d = Wv[((size_t)Tn * 8 + kc) * 64 + lane];
            *(v4u*)(Wlds + ((size_t)((slot * 8 + kc) * 64 + lane)) * 8) = d;
        }
    }
    __syncthreads();

    // streamed o-tile bases: S0: Tn=48+w, S1: Tn=56+w
    const v4u* __restrict__ ob0 = Wv + ((size_t)(48 + w) * 8) * 64 + lane;
    const v4u* __restrict__ ob1 = Wv + ((size_t)(56 + w) * 8) * 64 + lane;
    v8bf so0[4], so1[4];
#pragma unroll
    for (int j = 0; j < 4; ++j) {
        so0[j] = __builtin_bit_cast(v8bf, ob0[j * 64]);
        so1[j] = __builtin_bit_cast(v8bf, ob1[j * 64]);
    }

    float c_st[8];
#pragma unroll
    for (int i = 0; i < 8; ++i) c_st[i] = 0.0f;

    // x for t=0 (rows quad*4+r; lane-uniform across l4 -> broadcast loads)
    v4f xv;
#pragma unroll
    for (int r = 0; r < 4; ++r)
        xv[r] = x[(size_t)(r0 + quad * 4 + r) * TT];

    int cur = 0;
    for (int t = 0; t < TT; ++t) {
        const unsigned short* hb = hbuf[cur];
        unsigned short* hn_ = hbuf[cur ^ 1];

        // A-frags, swizzled: row l4, logical granule kc*4+quad at pos ^ l4
        v8bf afrag[8];
#pragma unroll
        for (int kc = 0; kc < 8; ++kc)
            afrag[kc] = __builtin_bit_cast(v8bf, *(const v4u*)(
                hb + l4 * 256 + (((kc * 4 + quad) ^ l4) & 31) * 8));

        // ---- group S=0: i,f regs; g LDS; o streamed ----
        {
            v4f ai, af2, ag, ao;
            INITG(0, ai, af2, ag, ao)
            STREAMTILE(ao, so0, ob0)        // o,S0 + refill (t+1 frags for kc>=4)
            MFMA8(ai, wres, 0)              // i,S0
            MFMA8(af2, wres, 8)             // f,S0
            LDSTILE(ag, w * 2 + 0)          // g,S0
            GATES(0, ai, af2, ag, ao)
        }
        // ---- group S=1 ----
        {
            v4f ai, af2, ag, ao;
            INITG(1, ai, af2, ag, ao)
            // x prefetch for t+1 (last xv use was INITG above); rides barrier
            {
                int tn = (t + 1 < TT) ? (t + 1) : t;
#pragma unroll
                for (int r = 0; r < 4; ++r)
                    xv[r] = x[(size_t)(r0 + quad * 4 + r) * TT + tn];
            }
            STREAMTILE(ao, so1, ob1)        // o,S1 + refill
            MFMA8(ai, wres, 16)             // i,S1
            MFMA8(af2, wres, 24)            // f,S1
            LDSTILE(ag, w * 2 + 1)          // g,S1
            GATES(1, ai, af2, ag, ao)
        }

        // LDS-only barrier: drain DS (h-writes) but NOT vmcnt -> o/x prefetch
        // stays in flight across the step boundary.
        asm volatile("s_waitcnt lgkmcnt(0)\n\ts_barrier" ::: "memory");
        cur ^= 1;
    }

    // Epilogue: out[b] = h_final . W_lin + b_lin (swizzled read-back)
    {
        int rrow = tid >> 5, s5 = tid & 31;            // row 0..15, unit-granule 0..31
        int pos = (s5 ^ rrow) & 31;
        float p = 0.0f;
#pragma unroll
        for (int jj = 0; jj < 8; ++jj) {
            int j = s5 * 8 + jj;
            p += bf2f(hbuf[cur][rrow * 256 + pos * 8 + jj]) * W_lin[j];
        }
        part[tid] = p;
    }
    __syncthreads();
    if (tid < 16) {
        float sum = 0.0f;
#pragma unroll
        for (int s = 0; s < 32; ++s) sum += part[tid * 32 + s];
        out[r0 + tid] = sum + b_lin[0];
    }
}

extern "C" void kernel_launch(void* const* d_in, const int* in_sizes, int n_in,
                              void* d_out, int out_size, void* d_ws, size_t ws_size,
                              hipStream_t stream) {
    const float* x     = (const float*)d_in[0];
    const float* W_ih  = (const float*)d_in[1];
    const float* W_hh  = (const float*)d_in[2];
    const float* b_ih  = (const float*)d_in[3];
    const float* b_hh  = (const float*)d_in[4];
    const float* W_lin = (const float*)d_in[5];
    const float* b_lin = (const float*)d_in[6];
    unsigned short* Wbf = (unsigned short*)d_ws;   // 512 KB

    wconv_kernel<<<128, 256, 0, stream>>>(W_hh, Wbf);
    lstm_kernel<<<NBLK, THREADS, 0, stream>>>(x, W_ih, b_ih, b_hh, W_lin, b_lin,
                                              Wbf, (float*)d_out);
}